// Round 19
// baseline (65.166 us; speedup 1.0000x reference)
//
#include <hip/hip_runtime.h>
#include <math.h>

// Problem constants: bs=32, en=256, dx=512, dz=256, heads=8, dh=32, L=1280.
//
// Mask is block-diagonal eyes: q<256 -> one-hot row; q=256+j -> exactly 4
// nonzeros {q, 512+j, 768+j, 1024+j}. Wk folded into the query side; pe-dot
// and bk-dot are constant across the 4 softmax candidates -> cancel.
// Needed per (b,j,h):  dR_m = sum_e raw_m*w,  dO = sum_e w,
// with w = wu[j,h,e] + wv[b,h,e].
//
// Pipeline (3 launches):
//   L1 k_uv_copy : proj blocks (288, 2-way e-split, 512 thr) INTERLEAVED
//                  with out0 state-copy blocks (512) -> copy streams while
//                  proj chains stall.
//   L2 k_w_onehot: 256 combined wu2+wv blocks (wv folded in, same wrow)
//                  interleaved 1-in-5 with 1024 one-hot streaming blocks.
//   L3 k_all     : round-16 verbatim (best timed): 512 blocks (16jt,32b),
//                  2 chunks of 128 e staged in LDS, wu2 from global/L2,
//                  in-LDS reduce -> softmax -> dependent outputs.
//
// ws layout (floats): uT[256f][256j]@0, vT[256f][32b]@65536,
// wu2[8][256e][256j]@73728, wv[32][8][256e]@598016.

// ---------------------------------------------------------------- k_uv_copy
// 800 blocks x 512 threads.
//  blk<576 && blk%2==0 -> proj block pid=blk/2 (0..287):
//    pid<256: uT[f][pid] = (Q[256+pid]@Wq)[f];  pid>=256: vT[f][b]=pe@Wq+bq.
//    e-loop split 2 ways (ep=t>>8), LDS combine.
//  else -> copy block cid (0..511): out0[b][e][0:256] = state, 16 e-rows.
__global__ __launch_bounds__(512)
void k_uv_copy(const float* __restrict__ Q, const float* __restrict__ Wq,
               const float* __restrict__ bq, const float* __restrict__ state,
               float* __restrict__ uT, float* __restrict__ vT,
               float* __restrict__ out0) {
  const int blk = blockIdx.x;
  const int t = threadIdx.x;
  const bool is_proj = (blk < 576) && ((blk & 1) == 0);
  if (is_proj) {
    const int pid = blk >> 1;      // 0..287
    __shared__ float row[256];
    __shared__ float part[512];
    if (t < 256) {
      float rv;
      if (pid < 256) {
        rv = Q[(256 + pid) * 256 + t];
      } else {
        const int b = pid - 256;
        // sinusoidal PE over the BATCH axis (faithful quirk): pos=b
        const float dv = expf(-9.210340371976184f * (float)((t >> 1) << 1) * (1.0f / 256.0f));
        const float ang = (float)b * dv;
        rv = (t & 1) ? cosf(ang) : sinf(ang);
      }
      row[t] = rv;
    }
    __syncthreads();
    const int f = t & 255;
    const int ep = t >> 8;         // 0..1: e in [ep*128, ep*128+128)
    float acc = (ep == 0 && pid >= 256) ? bq[f] : 0.0f;
    const int e0 = ep * 128;
    for (int e = 0; e < 128; ++e)
      acc += row[e0 + e] * Wq[(e0 + e) * 256 + f];
    part[t] = acc;
    __syncthreads();
    if (t < 256) {
      const float sum = part[t] + part[t + 256];
      if (pid < 256) uT[t * 256 + pid] = sum;
      else           vT[t * 32 + (pid - 256)] = sum;
    }
  } else {
    const int cid = (blk < 576) ? (blk >> 1) : (blk - 288);  // 0..511
    const int b = cid >> 4, eg = cid & 15;
    const int r = t >> 5;          // 0..15
    const int c = t & 31;          // 0..31 (float4 col)
    const int e = eg * 16 + r;
    const size_t base = ((size_t)(b * 256 + e)) * 512;
    *(float4*)(out0 + base + c * 4)        = *(const float4*)(state + base + c * 4);
    *(float4*)(out0 + base + (c + 32) * 4) = *(const float4*)(state + base + (c + 32) * 4);
  }
}

// ---------------------------------------------------------------- k_w_onehot
// 1280 blocks x 256 threads.
//  blk%5==0 -> compute block e=blk/5 (0..255): wu2 (all threads, coalesced
//              uT reads) THEN wv (threads<32, coalesced vT reads) — shares
//              the staged wrow.
//  else     -> one-hot streaming block cid (0..1023).
__global__ __launch_bounds__(256)
void k_w_onehot(const float* __restrict__ Wk, const float* __restrict__ uT,
                const float* __restrict__ vT, float* __restrict__ wu2,
                float* __restrict__ wv, float* __restrict__ out1) {
  const int blk = blockIdx.x;
  const int t = threadIdx.x;
  if (blk % 5 == 0) {
    const int e = blk / 5;         // 0..255
    __shared__ float wrow[256];
    wrow[t] = Wk[e * 256 + t];
    __syncthreads();
    // wu2: thread t = j; lane-coalesced uT reads
#pragma unroll
    for (int h = 0; h < 8; ++h) {
      float acc = 0.0f;
#pragma unroll
      for (int d = 0; d < 32; ++d)
        acc += uT[(h * 32 + d) * 256 + t] * wrow[h * 32 + d];
      wu2[(h * 256 + e) * 256 + t] = acc;
    }
    // wv: thread t = b (<32); lane-coalesced vT reads
    if (t < 32) {
#pragma unroll
      for (int h = 0; h < 8; ++h) {
        float acc = 0.0f;
#pragma unroll
        for (int d = 0; d < 32; ++d)
          acc += vT[(h * 32 + d) * 32 + t] * wrow[h * 32 + d];
        wv[(t * 8 + h) * 256 + e] = acc;
      }
    }
  } else {
    // one-hot rows q<256 (8 rows per block, 320 float4 per row)
    const int cid = blk - (blk / 5 + 1);  // 0..1023
    const int b = cid >> 5, qg = cid & 31;
#pragma unroll
    for (int k = 0; k < 8; ++k) {
      const int q = qg * 8 + k;
      float4* row = (float4*)(out1 + ((size_t)(b * 512 + q)) * 1280);
      float4 o = make_float4(0.f, 0.f, 0.f, 0.f);
      if (t == (q >> 2)) {
        const int comp = q & 3;
        if (comp == 0) o.x = 1.f; else if (comp == 1) o.y = 1.f;
        else if (comp == 2) o.z = 1.f; else o.w = 1.f;
      }
      row[t] = o;
      if (t < 64) row[256 + t] = make_float4(0.f, 0.f, 0.f, 0.f);
    }
  }
}

// ---------------------------------------------------------------- k_all
// Round-16 verbatim. grid (16 jt, 32 b) = 512 blocks, 512 threads = 8 waves,
// 58.9 KB LDS -> 2 blocks/CU, whole grid co-resident.
__global__ __launch_bounds__(512)
void k_all(const float* __restrict__ state, const float* __restrict__ o0,
           const float* __restrict__ o1, const float* __restrict__ o2,
           const float* __restrict__ wu2, const float* __restrict__ wv,
           float* __restrict__ out0, float* __restrict__ out1) {
  const int t = threadIdx.x;
  const int jt = blockIdx.x;       // 0..15
  const int b  = blockIdx.y;       // 0..31

  __shared__ float s_data[4][128][17];  // 34.8 KB (reused per chunk)
  __shared__ float s_wvb[2048];         //  8.0 KB  wv[b][h][e]
  __shared__ float s_part[8][16][25];   // 12.8 KB
  __shared__ float s_tot[44][16];       //  2.8 KB
  __shared__ float s_a[16][4];

  for (int i = t; i < 2048; i += 512) s_wvb[i] = wv[b * 2048 + i];

  const int jl = t & 15;
  const int es = (t >> 4) & 15;    // 0..15
  const int hp = t >> 8;           // 0..1
  const int j = jt * 16 + jl;

  float acc[24];
#pragma unroll
  for (int k = 0; k < 24; ++k) acc[k] = 0.f;

  const float* pwu = wu2 + (size_t)hp * 4 * 256 * 256 + j;  // + (hh*256+e)*256
  const float* pwvb = s_wvb + hp * 4 * 256;                 // + hh*256+e

#pragma unroll
  for (int chunk = 0; chunk < 2; ++chunk) {
    __syncthreads();               // protect s_data reuse (chunk 1)
#pragma unroll
    for (int rep = 0; rep < 4; ++rep) {
      const int c = t + rep * 512;   // 0..2047
      const int m = c >> 9;          // 0..3
      const int r = c & 511;
      const int e = r >> 2;          // 0..127
      const int jq = r & 3;          // 0..3
      const int ge = chunk * 128 + e;
      const int j0 = jt * 16 + jq * 4;
      const float* src;
      if (m == 0)      src = state + ((size_t)(b * 256 + ge)) * 512 + 256 + j0;
      else if (m == 1) src = o0 + ((size_t)(b * 256 + ge)) * 256 + j0;
      else if (m == 2) src = o1 + ((size_t)(b * 256 + ge)) * 256 + j0;
      else             src = o2 + ((size_t)(b * 256 + ge)) * 256 + j0;
      const float4 v4 = *(const float4*)src;
      const int jb = jq * 4;
      s_data[m][e][jb]   = v4.x; s_data[m][e][jb+1] = v4.y;
      s_data[m][e][jb+2] = v4.z; s_data[m][e][jb+3] = v4.w;
    }
    __syncthreads();

#pragma unroll
    for (int it = 0; it < 8; ++it) {
      const int el = it * 16 + es;   // 0..127 within chunk
      const int e = chunk * 128 + el;
      const float s  = s_data[0][el][jl];
      const float x0 = s_data[1][el][jl];
      const float x1 = s_data[2][el][jl];
      const float x2 = s_data[3][el][jl];
      acc[20] += s; acc[21] += x0; acc[22] += x1; acc[23] += x2;
#pragma unroll
      for (int hh = 0; hh < 4; ++hh) {
        const float w = pwu[(size_t)(hh * 256 + e) * 256] + pwvb[hh * 256 + e];
        acc[hh * 5 + 0] += s * w;  acc[hh * 5 + 1] += x0 * w;
        acc[hh * 5 + 2] += x1 * w; acc[hh * 5 + 3] += x2 * w;
        acc[hh * 5 + 4] += w;
      }
    }
  }

  // reduce over es low bits (lane bits 4,5)
#pragma unroll
  for (int k = 0; k < 24; ++k) {
    acc[k] += __shfl_xor(acc[k], 16);
    acc[k] += __shfl_xor(acc[k], 32);
  }
  if ((t & 48) == 0) {
    const int w = t >> 6;          // 0..7
    float* p = &s_part[w][jl][0];
#pragma unroll
    for (int k = 0; k < 24; ++k) p[k] = acc[k];
  }
  __syncthreads();

  if (t < 16) {
#pragma unroll
    for (int k = 0; k < 20; ++k)
      s_tot[k][t] = s_part[0][t][k] + s_part[1][t][k] + s_part[2][t][k] + s_part[3][t][k];
#pragma unroll
    for (int c = 0; c < 4; ++c)
      s_tot[40 + c][t] = s_part[0][t][20 + c] + s_part[1][t][20 + c] +
                         s_part[2][t][20 + c] + s_part[3][t][20 + c];
  } else if (t >= 256 && t < 272) {
    const int l = t & 15;
#pragma unroll
    for (int k = 0; k < 20; ++k)
      s_tot[20 + k][l] = s_part[4][l][k] + s_part[5][l][k] + s_part[6][l][k] + s_part[7][l][k];
  }
  __syncthreads();

  if (t < 16) {
    float tot[44];
#pragma unroll
    for (int k = 0; k < 44; ++k) tot[k] = s_tot[k][t];
    const float m0 = tot[40] * (1.f / 256.f), m1 = tot[41] * (1.f / 256.f);
    const float m2 = tot[42] * (1.f / 256.f), m3 = tot[43] * (1.f / 256.f);
    const float inv = 0.17677669529663687f;  // 1/sqrt(32)
    float am0 = 0.f, am1 = 0.f, am2 = 0.f, am3 = 0.f;
#pragma unroll
    for (int h = 0; h < 8; ++h) {
      const float dO = tot[h * 5 + 4];
      const float s0 = (tot[h * 5 + 0] - m0 * dO) * inv;
      const float s1 = (tot[h * 5 + 1] - m1 * dO) * inv;
      const float s2 = (tot[h * 5 + 2] - m2 * dO) * inv;
      const float s3 = (tot[h * 5 + 3] - m3 * dO) * inv;
      const float mx = fmaxf(fmaxf(s0, s1), fmaxf(s2, s3));
      const float e0 = expf(s0 - mx), e1 = expf(s1 - mx);
      const float e2 = expf(s2 - mx), e3 = expf(s3 - mx);
      const float r = 1.f / (e0 + e1 + e2 + e3);
      am0 += e0 * r; am1 += e1 * r; am2 += e2 * r; am3 += e3 * r;
    }
    s_a[t][0] = am0 * 0.125f; s_a[t][1] = am1 * 0.125f;
    s_a[t][2] = am2 * 0.125f; s_a[t][3] = am3 * 0.125f;
  }
  __syncthreads();

  // ---- out0[b][e][256+j] (raw inputs L2-hot: this block just read them)
  {
    const int jl2 = t & 15;
    const int er = t >> 4;         // 0..31
    const float a0 = s_a[jl2][0], a1 = s_a[jl2][1];
    const float a2 = s_a[jl2][2], a3 = s_a[jl2][3];
    const int jj = jt * 16 + jl2;
#pragma unroll
    for (int k = 0; k < 8; ++k) {
      const int e = er + 32 * k;
      const size_t idxS = ((size_t)(b * 256 + e)) * 512 + 256 + jj;
      const size_t idxO = ((size_t)(b * 256 + e)) * 256 + jj;
      out0[idxS] = a0 * state[idxS] + a1 * o0[idxO] + a2 * o1[idxO] + a3 * o2[idxO];
    }
  }

  // ---- out1 rows q = 256+j (4 sparse values, rest zero)
  {
    const int r = t >> 5;          // 0..15 (row within tile)
    const int c = t & 31;
    const int j3 = jt * 16 + r;
    const int q = 256 + j3;
    const int comp = j3 & 3;
    const int tc0 = (256 + j3) >> 2, tc1 = (512 + j3) >> 2;
    const int tc2 = (768 + j3) >> 2, tc3 = (1024 + j3) >> 2;
    const float av0 = s_a[r][0], av1 = s_a[r][1];
    const float av2 = s_a[r][2], av3 = s_a[r][3];
    float4* orow = (float4*)(out1 + ((size_t)(b * 512 + q)) * 1280);
#pragma unroll
    for (int k = 0; k < 10; ++k) {
      const int c4 = c + 32 * k;
      float4 o = make_float4(0.f, 0.f, 0.f, 0.f);
      float val = 0.f; bool hit = false;
      if (c4 == tc0)      { val = av0; hit = true; }
      else if (c4 == tc1) { val = av1; hit = true; }
      else if (c4 == tc2) { val = av2; hit = true; }
      else if (c4 == tc3) { val = av3; hit = true; }
      if (hit) {
        if (comp == 0) o.x = val; else if (comp == 1) o.y = val;
        else if (comp == 2) o.z = val; else o.w = val;
      }
      orow[c4] = o;
    }
  }
}

extern "C" void kernel_launch(void* const* d_in, const int* in_sizes, int n_in,
                              void* d_out, int out_size, void* d_ws, size_t ws_size,
                              hipStream_t stream) {
  const float* state = (const float*)d_in[0];
  const float* obs0  = (const float*)d_in[1];
  const float* obs1  = (const float*)d_in[2];
  const float* obs2  = (const float*)d_in[3];
  const float* Q     = (const float*)d_in[4];
  const float* Wq    = (const float*)d_in[5];
  const float* bq    = (const float*)d_in[6];
  const float* Wk    = (const float*)d_in[7];
  // d_in[8] = bk: cancels in the 4-way softmax (shift invariance), unused.

  float* out0 = (float*)d_out;                       // new_state [32,256,512]
  float* out1 = out0 + (size_t)32 * 256 * 512;       // atten [32,512,1280]

  float* ws  = (float*)d_ws;
  float* uT  = ws;              // 65536  [256f][256j]
  float* vT  = uT + 65536;      // 8192   [256f][32b]
  float* wu2 = vT + 8192;       // 524288
  float* wv  = wu2 + 524288;    // 65536

  k_uv_copy<<<800, 512, 0, stream>>>(Q, Wq, bq, state, uT, vT, out0);
  k_w_onehot<<<1280, 256, 0, stream>>>(Wk, uT, vT, wu2, wv, out1);
  k_all<<<dim3(16, 32), 512, 0, stream>>>(state, obs0, obs1, obs2, wu2, wv, out0, out1);
}